// Round 3
// baseline (574.242 us; speedup 1.0000x reference)
//
#include <hip/hip_runtime.h>
#include <hip/hip_bf16.h>
#include <cstdint>

#define TOKENS 8192
#define IN_F 4096
#define OUT_F 4096

typedef __bf16 bf16x8 __attribute__((ext_vector_type(8)));
typedef float f32x4 __attribute__((ext_vector_type(4)));

// ---------------------------------------------------------------------------
// Last-write-wins scatter: M[cell] = max nnz-index touching cell.
// ---------------------------------------------------------------------------
__global__ void scatter_max_kernel(const int* __restrict__ row,
                                   const int* __restrict__ col,
                                   int* __restrict__ M, int nnz) {
    int i = blockIdx.x * blockDim.x + threadIdx.x;
    if (i < nnz) {
        atomicMax(&M[(size_t)row[i] * IN_F + col[i]], i);
    }
}

// ---------------------------------------------------------------------------
// Fused streaming pass: extract winning weights -> bf16 W; convert x -> bf16.
// ---------------------------------------------------------------------------
__global__ void extract_convert_kernel(const int* __restrict__ M,
                                       const float* __restrict__ w,
                                       __bf16* __restrict__ Wb,
                                       const float* __restrict__ x,
                                       __bf16* __restrict__ xb,
                                       int eb) {
    if ((int)blockIdx.x < eb) {
        size_t base = ((size_t)blockIdx.x * 256 + threadIdx.x) * 8;
        int4 m0 = *(const int4*)(M + base);
        int4 m1 = *(const int4*)(M + base + 4);
        int idx[8] = {m0.x, m0.y, m0.z, m0.w, m1.x, m1.y, m1.z, m1.w};
        bf16x8 o;
#pragma unroll
        for (int j = 0; j < 8; ++j) {
            o[j] = (idx[j] >= 0) ? (__bf16)w[idx[j]] : (__bf16)0.0f;
        }
        *(bf16x8*)(Wb + base) = o;
    } else {
        size_t base = ((size_t)(blockIdx.x - eb) * 256 + threadIdx.x) * 8;
        float4 v0 = *(const float4*)(x + base);
        float4 v1 = *(const float4*)(x + base + 4);
        bf16x8 o;
        o[0] = (__bf16)v0.x; o[1] = (__bf16)v0.y;
        o[2] = (__bf16)v0.z; o[3] = (__bf16)v0.w;
        o[4] = (__bf16)v1.x; o[5] = (__bf16)v1.y;
        o[6] = (__bf16)v1.z; o[7] = (__bf16)v1.w;
        *(bf16x8*)(xb + base) = o;
    }
}

// ---------------------------------------------------------------------------
// GEMM v3: C = A*B^T + bias. 256x256 tile, BK=64, 8 waves (2Mx4N), 128KiB LDS.
//
// Uniform 4-phase-per-tile pipeline, read-ahead-1, ONE barrier per phase:
//   phase = { 6 ds_read_b128 (next MMA's operands) | 2 global_load_lds |
//             16 MFMA (operands from prev phase, already landed) |
//             lgkmcnt(0) [free: post-MMA] | [vmcnt(2) gate @T2 only] | barrier }
// MMA never waits on same-phase reads -> LDS read latency/BW hides under MFMA.
// vmcnt is COUNTED (2), never 0, and only drains loads >= 2 phases old.
//
// LDS layout: buf X (64KiB) = [A 32KiB | B 32KiB] at X*64KiB, so every
// ds_read is base+16-bit-immediate. Swizzle: physical 16B chunk p of row r
// holds logical chunk p^(r&7); staged via pre-swizzled GLOBAL source column
// (linear global_load_lds dest), read with chunk (kk*4+(l>>4))^(l&7).
//
// Per tile s (buf X=s&1, Y=1-X; b01 regs ping-pong E/O across tiles):
//  T1: rd b23(s)@X, a1.mf0(s)@X   | st A(s+1)#2->Y | MMA a0(s) x b01cur
//  T2: rd a1.mf1-3(s)@X           | st B(s+2)#1->X | MMA a0(s) x b23   | vm(2)
//  T3: rd a0(s+1).mf0-2@Y         | st B(s+2)#2->X | MMA a1(s) x b23
//  T4: rd a0(s+1).mf3, b01(s+1)@Y | st A(s+2)#1->X | MMA a1(s) x b01cur
// Region-safety: every stage lands in a region whose last ds_read was >= 1
// phase earlier (that phase's lgkmcnt(0)+barrier drained it across waves).
// vmcnt(2)@T2-end + barrier certifies tile s+1's A#1/A#2/B stages (issued
// (s-1).T4, s.T1, (s-1).T2/T3) landed before T3/T4 read buf Y.
// ---------------------------------------------------------------------------
#define BK 64
#define NT (IN_F / BK)

__global__ __launch_bounds__(512, 1) void gemm256_kernel(
    const __bf16* __restrict__ A,   // [TOKENS, IN_F] bf16
    const __bf16* __restrict__ B,   // [OUT_F, IN_F] bf16
    const float* __restrict__ bias, // [OUT_F]
    float* __restrict__ C) {        // [TOKENS, OUT_F]
    extern __shared__ __bf16 sm[];  // buf0 @0: A|B ; buf1 @32768 elems: A|B

    const int tid = threadIdx.x;
    const int l   = tid & 63;
    const int wid = tid >> 6;        // 0..7
    const int wm  = wid >> 2;        // 0..1
    const int wn  = wid & 3;         // 0..3

    // XCD-aware swizzle: 512 wgs, divisible by 8 -> bijective.
    const int bid = blockIdx.y * 16 + blockIdx.x;
    const int swz = (bid & 7) * 64 + (bid >> 3);
    const int n0 = (swz & 15) * 256;
    const int m0 = (swz >> 4) * 256;

    // Staging: lane covers row tid>>3 of each 64-row group; source 16B-chunk
    // pre-swizzled so linear LDS slot (r,p) holds logical chunk p^(r&7).
    const int srow   = tid >> 3;
    const int schunk = (tid & 7) ^ (srow & 7);
    const __bf16* gA = A + (size_t)(m0 + srow) * IN_F + schunk * 8;
    const __bf16* gB = B + (size_t)(n0 + srow) * IN_F + schunk * 8;
    const int ldsw = wid * 512;

#define GLD(SRC, LEL)                                                          \
    __builtin_amdgcn_global_load_lds(                                          \
        (unsigned int __attribute__((address_space(1)))*)(SRC),                \
        (unsigned int __attribute__((address_space(3)))*)(sm + (LEL)), 16, 0, 0);

#define STAGE_A_H1(X, KT) {                                                    \
    GLD(gA + (KT),              (X)*32768 + 0    + ldsw)                       \
    GLD(gA + 64*IN_F  + (KT),   (X)*32768 + 4096 + ldsw) }
#define STAGE_A_H2(X, KT) {                                                    \
    GLD(gA + 128*IN_F + (KT),   (X)*32768 + 8192  + ldsw)                      \
    GLD(gA + 192*IN_F + (KT),   (X)*32768 + 12288 + ldsw) }
#define STAGE_B_H1(X, KT) {                                                    \
    GLD(gB + (KT),              (X)*32768 + 16384 + 0    + ldsw)               \
    GLD(gB + 64*IN_F  + (KT),   (X)*32768 + 16384 + 4096 + ldsw) }
#define STAGE_B_H2(X, KT) {                                                    \
    GLD(gB + 128*IN_F + (KT),   (X)*32768 + 16384 + 8192  + ldsw)              \
    GLD(gB + 192*IN_F + (KT),   (X)*32768 + 16384 + 12288 + ldsw) }

    // Fragment addressing: logical chunk kk*4 + (l>>4), physical = ^ (l&7).
    const int g    = l >> 4;
    const int fr   = l & 15;
    const int ch0  = g ^ (l & 7);
    const int ch1  = ch0 ^ 4;
    const int arow = (wm * 128 + fr) * 64;   // elem offset within buf A-region
    const int brow = (wn * 64 + fr) * 64;    // elem offset within buf B-region

    f32x4 acc[8][4] = {};
    bf16x8 a0f[4][2], a1f[4][2], b01E[2][2], b01O[2][2], b23[2][2];

#define LDAF(DST, MF, X, MH) {                                                               \
    DST[MF][0] = *(const bf16x8*)(sm + (X)*32768 + (MH)*4096 + arow + (MF)*1024 + ch0*8);    \
    DST[MF][1] = *(const bf16x8*)(sm + (X)*32768 + (MH)*4096 + arow + (MF)*1024 + ch1*8); }

#define LDBF(DST, J, X, NB) {                                                                      \
    DST[J][0] = *(const bf16x8*)(sm + (X)*32768 + 16384 + brow + ((NB)+(J))*1024 + ch0*8);         \
    DST[J][1] = *(const bf16x8*)(sm + (X)*32768 + 16384 + brow + ((NB)+(J))*1024 + ch1*8); }

// kk-outer: 8-instruction dependency distance on each acc chain.
#define MMA_Q(AR, MH, BR, NB) {                                                \
    __builtin_amdgcn_s_setprio(1);                                             \
    _Pragma("unroll") for (int kk = 0; kk < 2; ++kk)                           \
    _Pragma("unroll") for (int mf = 0; mf < 4; ++mf)                           \
    _Pragma("unroll") for (int j = 0; j < 2; ++j)                              \
        acc[(MH)*4+mf][(NB)+j] = __builtin_amdgcn_mfma_f32_16x16x32_bf16(      \
            AR[mf][kk], BR[j][kk], acc[(MH)*4+mf][(NB)+j], 0, 0, 0);           \
    __builtin_amdgcn_s_setprio(0); }

#define BAR()      __builtin_amdgcn_s_barrier();
#define LGKM0      asm volatile("s_waitcnt lgkmcnt(0)" ::: "memory");
#define LGKM0VM2   asm volatile("s_waitcnt vmcnt(2) lgkmcnt(0)" ::: "memory");

#define TILE(X, BC, BN, KA1, KAB2) {                                           \
    /* T1 */                                                                   \
    LDBF(b23, 0, X, 2) LDBF(b23, 1, X, 2) LDAF(a1f, 0, X, 1)                   \
    STAGE_A_H2(1-(X), KA1)                                                     \
    MMA_Q(a0f, 0, BC, 0)                                                       \
    LGKM0 BAR()                                                                \
    /* T2 */                                                                   \
    LDAF(a1f, 1, X, 1) LDAF(a1f, 2, X, 1) LDAF(a1f, 3, X, 1)                   \
    STAGE_B_H1(X, KAB2)                                                        \
    MMA_Q(a0f, 0, b23, 2)                                                      \
    LGKM0VM2 BAR()                                                             \
    /* T3 */                                                                   \
    LDAF(a0f, 0, 1-(X), 0) LDAF(a0f, 1, 1-(X), 0) LDAF(a0f, 2, 1-(X), 0)       \
    STAGE_B_H2(X, KAB2)                                                        \
    MMA_Q(a1f, 1, b23, 2)                                                      \
    LGKM0 BAR()                                                                \
    /* T4 */                                                                   \
    LDAF(a0f, 3, 1-(X), 0) LDBF(BN, 0, 1-(X), 0) LDBF(BN, 1, 1-(X), 0)         \
    STAGE_A_H1(X, KAB2)                                                        \
    MMA_Q(a1f, 1, BC, 0)                                                       \
    LGKM0 BAR() }

    // Prologue: A(0),B(0)->buf0 (8), B(1)->buf1 (4), A(1)#1->buf1 (2) = 14.
    // vmcnt(6) waits the 8 oldest = tile 0 complete; then pre-read tile-0
    // a0 + b01 so tile0.T1's MMA has operands.
    STAGE_A_H1(0, 0) STAGE_A_H2(0, 0) STAGE_B_H1(0, 0) STAGE_B_H2(0, 0)
    STAGE_B_H1(1, BK) STAGE_B_H2(1, BK) STAGE_A_H1(1, BK)
    asm volatile("s_waitcnt vmcnt(6)" ::: "memory");
    BAR()
    LDAF(a0f, 0, 0, 0) LDAF(a0f, 1, 0, 0) LDAF(a0f, 2, 0, 0) LDAF(a0f, 3, 0, 0)
    LDBF(b01E, 0, 0, 0) LDBF(b01E, 1, 0, 0)

#pragma unroll 1
    for (int t = 0; t < NT; t += 2) {
        const int ka1  = ((t + 1) & (NT - 1)) * BK;
        const int kab2 = ((t + 2) & (NT - 1)) * BK;  // wraps harmlessly at tail
        const int kab3 = ((t + 3) & (NT - 1)) * BK;
        TILE(0, b01E, b01O, ka1, kab2)
        TILE(1, b01O, b01E, kab2, kab3)
    }
    asm volatile("s_waitcnt vmcnt(0) lgkmcnt(0)" ::: "memory");

    // Epilogue: C/D layout col = l&15, row = (l>>4)*4 + i. Nontemporal
    // stores: C (134MB) is write-once -- keep it from evicting xb/Wb in L2/L3.
    float bv[4];
#pragma unroll
    for (int nf = 0; nf < 4; ++nf) bv[nf] = bias[n0 + wn * 64 + nf * 16 + fr];
    const int r0 = m0 + wm * 128 + g * 4;
#pragma unroll
    for (int mh = 0; mh < 2; ++mh)
#pragma unroll
        for (int mf = 0; mf < 4; ++mf)
#pragma unroll
            for (int nf = 0; nf < 4; ++nf) {
                const int col = n0 + wn * 64 + nf * 16 + fr;
#pragma unroll
                for (int i = 0; i < 4; ++i)
                    __builtin_nontemporal_store(
                        acc[mh * 4 + mf][nf][i] + bv[nf],
                        &C[(size_t)(r0 + mh * 64 + mf * 16 + i) * OUT_F + col]);
            }
}

extern "C" void kernel_launch(void* const* d_in, const int* in_sizes, int n_in,
                              void* d_out, int out_size, void* d_ws, size_t ws_size,
                              hipStream_t stream) {
    const float* x    = (const float*)d_in[0];
    const float* w    = (const float*)d_in[1];
    const float* bias = (const float*)d_in[2];
    const int*   row  = (const int*)d_in[3];
    const int*   col  = (const int*)d_in[4];
    float* out = (float*)d_out;
    const int nnz = in_sizes[3];

    // Workspace: xb (67 MB) + Wb (33.5 MB) in d_ws. Winner-index array M
    // (67 MB) borrows d_out (134 MB) -- GEMM overwrites it later.
    __bf16* xb = (__bf16*)d_ws;
    __bf16* Wb = (__bf16*)((char*)d_ws + (size_t)TOKENS * IN_F * 2);
    int* M = (int*)d_out;

    static bool attr_done = false;
    if (!attr_done) {
        hipFuncSetAttribute(reinterpret_cast<const void*>(gemm256_kernel),
                            hipFuncAttributeMaxDynamicSharedMemorySize, 131072);
        attr_done = true;
    }

    hipMemsetAsync(M, 0xFF, (size_t)OUT_F * IN_F * 4, stream);  // M = -1

    scatter_max_kernel<<<(nnz + 255) / 256, 256, 0, stream>>>(row, col, M, nnz);

    const int eb = OUT_F * IN_F / (256 * 8);        // 8192 extract blocks
    const int cb = TOKENS * IN_F / (256 * 8);       // 16384 convert blocks
    extract_convert_kernel<<<eb + cb, 256, 0, stream>>>(M, w, Wb, x, xb, eb);

    dim3 grid(OUT_F / 256, TOKENS / 256);           // (16, 32) = 512 wgs
    gemm256_kernel<<<grid, 512, 131072, stream>>>(xb, Wb, bias, out);
}

// Round 4
// 573.443 us; speedup vs baseline: 1.0014x; 1.0014x over previous
//
#include <hip/hip_runtime.h>
#include <hip/hip_bf16.h>
#include <cstdint>

#define TOKENS 8192
#define IN_F 4096
#define OUT_F 4096

typedef __bf16 bf16x8 __attribute__((ext_vector_type(8)));
typedef float f32x4 __attribute__((ext_vector_type(4)));

// ---------------------------------------------------------------------------
// Fused pass 1: blocks [0, sb) scatter packed (idx+1)<<32 | fp32bits(w) via
// 64-bit atomicMax into P (last-write-wins == max nnz index; payload carries
// the winning weight, so no gather is ever needed). Blocks [sb, ...) stream
// x fp32 -> bf16. The scatter is latency-bound; the convert fills HBM BW
// concurrently in the same dispatch.
// ---------------------------------------------------------------------------
__global__ void fused_scatter_convert_kernel(const int* __restrict__ row,
                                             const int* __restrict__ col,
                                             const float* __restrict__ w,
                                             unsigned long long* __restrict__ P,
                                             const float* __restrict__ x,
                                             __bf16* __restrict__ xb,
                                             int sb, int nnz) {
    if ((int)blockIdx.x < sb) {
        int base = (blockIdx.x * 256 + threadIdx.x) * 4;
        if (base + 3 < nnz) {
            int4   r4 = *(const int4*)(row + base);
            int4   c4 = *(const int4*)(col + base);
            float4 w4 = *(const float4*)(w + base);
            atomicMax(&P[(size_t)r4.x * IN_F + c4.x],
                      ((unsigned long long)(base + 1) << 32) | __float_as_uint(w4.x));
            atomicMax(&P[(size_t)r4.y * IN_F + c4.y],
                      ((unsigned long long)(base + 2) << 32) | __float_as_uint(w4.y));
            atomicMax(&P[(size_t)r4.z * IN_F + c4.z],
                      ((unsigned long long)(base + 3) << 32) | __float_as_uint(w4.z));
            atomicMax(&P[(size_t)r4.w * IN_F + c4.w],
                      ((unsigned long long)(base + 4) << 32) | __float_as_uint(w4.w));
        } else {
            for (int i = base; i < nnz; ++i) {
                atomicMax(&P[(size_t)row[i] * IN_F + col[i]],
                          ((unsigned long long)(i + 1) << 32) | __float_as_uint(w[i]));
            }
        }
    } else {
        size_t base = ((size_t)(blockIdx.x - sb) * 256 + threadIdx.x) * 8;
        float4 v0 = *(const float4*)(x + base);
        float4 v1 = *(const float4*)(x + base + 4);
        bf16x8 o;
        o[0] = (__bf16)v0.x; o[1] = (__bf16)v0.y;
        o[2] = (__bf16)v0.z; o[3] = (__bf16)v0.w;
        o[4] = (__bf16)v1.x; o[5] = (__bf16)v1.y;
        o[6] = (__bf16)v1.z; o[7] = (__bf16)v1.w;
        *(bf16x8*)(xb + base) = o;
    }
}

// ---------------------------------------------------------------------------
// Pass 2: pure streaming extract P -> bf16 W. hi32==0 means untouched cell.
// ---------------------------------------------------------------------------
__global__ void extract_kernel(const unsigned long long* __restrict__ P,
                               __bf16* __restrict__ Wb) {
    size_t base = ((size_t)blockIdx.x * 256 + threadIdx.x) * 8;
    bf16x8 o;
#pragma unroll
    for (int j = 0; j < 4; ++j) {
        ulonglong2 p = *(const ulonglong2*)(P + base + j * 2);
        o[j * 2]     = (p.x >> 32) ? (__bf16)__uint_as_float((unsigned)p.x) : (__bf16)0.0f;
        o[j * 2 + 1] = (p.y >> 32) ? (__bf16)__uint_as_float((unsigned)p.y) : (__bf16)0.0f;
    }
    *(bf16x8*)(Wb + base) = o;
}

// ---------------------------------------------------------------------------
// GEMM v3 (sans NT stores): C = A*B^T + bias. 256x256 tile, BK=64, 8 waves
// (2Mx4N), 128KiB LDS. Uniform 4-phase pipeline, read-ahead-1, one barrier
// per phase; counted vmcnt(2) once per tile. See R2/R3 notes; schedule
// measured neutral vs R1 at MfmaUtil ~46%.
// ---------------------------------------------------------------------------
#define BK 64
#define NT (IN_F / BK)

__global__ __launch_bounds__(512, 1) void gemm256_kernel(
    const __bf16* __restrict__ A,   // [TOKENS, IN_F] bf16
    const __bf16* __restrict__ B,   // [OUT_F, IN_F] bf16
    const float* __restrict__ bias, // [OUT_F]
    float* __restrict__ C) {        // [TOKENS, OUT_F]
    extern __shared__ __bf16 sm[];  // buf0 @0: A|B ; buf1 @32768 elems: A|B

    const int tid = threadIdx.x;
    const int l   = tid & 63;
    const int wid = tid >> 6;        // 0..7
    const int wm  = wid >> 2;        // 0..1
    const int wn  = wid & 3;         // 0..3

    // XCD-aware swizzle: 512 wgs, divisible by 8 -> bijective.
    const int bid = blockIdx.y * 16 + blockIdx.x;
    const int swz = (bid & 7) * 64 + (bid >> 3);
    const int n0 = (swz & 15) * 256;
    const int m0 = (swz >> 4) * 256;

    // Staging: lane covers row tid>>3 of each 64-row group; source 16B-chunk
    // pre-swizzled so linear LDS slot (r,p) holds logical chunk p^(r&7).
    const int srow   = tid >> 3;
    const int schunk = (tid & 7) ^ (srow & 7);
    const __bf16* gA = A + (size_t)(m0 + srow) * IN_F + schunk * 8;
    const __bf16* gB = B + (size_t)(n0 + srow) * IN_F + schunk * 8;
    const int ldsw = wid * 512;

#define GLD(SRC, LEL)                                                          \
    __builtin_amdgcn_global_load_lds(                                          \
        (unsigned int __attribute__((address_space(1)))*)(SRC),                \
        (unsigned int __attribute__((address_space(3)))*)(sm + (LEL)), 16, 0, 0);

#define STAGE_A_H1(X, KT) {                                                    \
    GLD(gA + (KT),              (X)*32768 + 0    + ldsw)                       \
    GLD(gA + 64*IN_F  + (KT),   (X)*32768 + 4096 + ldsw) }
#define STAGE_A_H2(X, KT) {                                                    \
    GLD(gA + 128*IN_F + (KT),   (X)*32768 + 8192  + ldsw)                      \
    GLD(gA + 192*IN_F + (KT),   (X)*32768 + 12288 + ldsw) }
#define STAGE_B_H1(X, KT) {                                                    \
    GLD(gB + (KT),              (X)*32768 + 16384 + 0    + ldsw)               \
    GLD(gB + 64*IN_F  + (KT),   (X)*32768 + 16384 + 4096 + ldsw) }
#define STAGE_B_H2(X, KT) {                                                    \
    GLD(gB + 128*IN_F + (KT),   (X)*32768 + 16384 + 8192  + ldsw)              \
    GLD(gB + 192*IN_F + (KT),   (X)*32768 + 16384 + 12288 + ldsw) }

    // Fragment addressing: logical chunk kk*4 + (l>>4), physical = ^ (l&7).
    const int g    = l >> 4;
    const int fr   = l & 15;
    const int ch0  = g ^ (l & 7);
    const int ch1  = ch0 ^ 4;
    const int arow = (wm * 128 + fr) * 64;   // elem offset within buf A-region
    const int brow = (wn * 64 + fr) * 64;    // elem offset within buf B-region

    f32x4 acc[8][4] = {};
    bf16x8 a0f[4][2], a1f[4][2], b01E[2][2], b01O[2][2], b23[2][2];

#define LDAF(DST, MF, X, MH) {                                                               \
    DST[MF][0] = *(const bf16x8*)(sm + (X)*32768 + (MH)*4096 + arow + (MF)*1024 + ch0*8);    \
    DST[MF][1] = *(const bf16x8*)(sm + (X)*32768 + (MH)*4096 + arow + (MF)*1024 + ch1*8); }

#define LDBF(DST, J, X, NB) {                                                                      \
    DST[J][0] = *(const bf16x8*)(sm + (X)*32768 + 16384 + brow + ((NB)+(J))*1024 + ch0*8);         \
    DST[J][1] = *(const bf16x8*)(sm + (X)*32768 + 16384 + brow + ((NB)+(J))*1024 + ch1*8); }

// kk-outer: 8-instruction dependency distance on each acc chain.
#define MMA_Q(AR, MH, BR, NB) {                                                \
    __builtin_amdgcn_s_setprio(1);                                             \
    _Pragma("unroll") for (int kk = 0; kk < 2; ++kk)                           \
    _Pragma("unroll") for (int mf = 0; mf < 4; ++mf)                           \
    _Pragma("unroll") for (int j = 0; j < 2; ++j)                              \
        acc[(MH)*4+mf][(NB)+j] = __builtin_amdgcn_mfma_f32_16x16x32_bf16(      \
            AR[mf][kk], BR[j][kk], acc[(MH)*4+mf][(NB)+j], 0, 0, 0);           \
    __builtin_amdgcn_s_setprio(0); }

#define BAR()      __builtin_amdgcn_s_barrier();
#define LGKM0      asm volatile("s_waitcnt lgkmcnt(0)" ::: "memory");
#define LGKM0VM2   asm volatile("s_waitcnt vmcnt(2) lgkmcnt(0)" ::: "memory");

#define TILE(X, BC, BN, KA1, KAB2) {                                           \
    /* T1 */                                                                   \
    LDBF(b23, 0, X, 2) LDBF(b23, 1, X, 2) LDAF(a1f, 0, X, 1)                   \
    STAGE_A_H2(1-(X), KA1)                                                     \
    MMA_Q(a0f, 0, BC, 0)                                                       \
    LGKM0 BAR()                                                                \
    /* T2 */                                                                   \
    LDAF(a1f, 1, X, 1) LDAF(a1f, 2, X, 1) LDAF(a1f, 3, X, 1)                   \
    STAGE_B_H1(X, KAB2)                                                        \
    MMA_Q(a0f, 0, b23, 2)                                                      \
    LGKM0VM2 BAR()                                                             \
    /* T3 */                                                                   \
    LDAF(a0f, 0, 1-(X), 0) LDAF(a0f, 1, 1-(X), 0) LDAF(a0f, 2, 1-(X), 0)       \
    STAGE_B_H2(X, KAB2)                                                        \
    MMA_Q(a1f, 1, b23, 2)                                                      \
    LGKM0 BAR()                                                                \
    /* T4 */                                                                   \
    LDAF(a0f, 3, 1-(X), 0) LDBF(BN, 0, 1-(X), 0) LDBF(BN, 1, 1-(X), 0)         \
    STAGE_A_H1(X, KAB2)                                                        \
    MMA_Q(a1f, 1, BC, 0)                                                       \
    LGKM0 BAR() }

    // Prologue: A(0),B(0)->buf0 (8), B(1)->buf1 (4), A(1)#1->buf1 (2) = 14.
    // vmcnt(6) waits the 8 oldest = tile 0 complete; then pre-read tile-0
    // a0 + b01 so tile0.T1's MMA has operands.
    STAGE_A_H1(0, 0) STAGE_A_H2(0, 0) STAGE_B_H1(0, 0) STAGE_B_H2(0, 0)
    STAGE_B_H1(1, BK) STAGE_B_H2(1, BK) STAGE_A_H1(1, BK)
    asm volatile("s_waitcnt vmcnt(6)" ::: "memory");
    BAR()
    LDAF(a0f, 0, 0, 0) LDAF(a0f, 1, 0, 0) LDAF(a0f, 2, 0, 0) LDAF(a0f, 3, 0, 0)
    LDBF(b01E, 0, 0, 0) LDBF(b01E, 1, 0, 0)

#pragma unroll 1
    for (int t = 0; t < NT; t += 2) {
        const int ka1  = ((t + 1) & (NT - 1)) * BK;
        const int kab2 = ((t + 2) & (NT - 1)) * BK;  // wraps harmlessly at tail
        const int kab3 = ((t + 3) & (NT - 1)) * BK;
        TILE(0, b01E, b01O, ka1, kab2)
        TILE(1, b01O, b01E, kab2, kab3)
    }
    asm volatile("s_waitcnt vmcnt(0) lgkmcnt(0)" ::: "memory");

    // Epilogue: C/D layout col = l&15, row = (l>>4)*4 + i. Plain stores
    // (NT stores measured +50MB WRITE_SIZE / +27us in R3 -- reverted).
    float bv[4];
#pragma unroll
    for (int nf = 0; nf < 4; ++nf) bv[nf] = bias[n0 + wn * 64 + nf * 16 + fr];
    const int r0 = m0 + wm * 128 + g * 4;
#pragma unroll
    for (int mh = 0; mh < 2; ++mh)
#pragma unroll
        for (int mf = 0; mf < 4; ++mf)
#pragma unroll
            for (int nf = 0; nf < 4; ++nf) {
                const int col = n0 + wn * 64 + nf * 16 + fr;
#pragma unroll
                for (int i = 0; i < 4; ++i)
                    C[(size_t)(r0 + mh * 64 + mf * 16 + i) * OUT_F + col] =
                        acc[mh * 4 + mf][nf][i] + bv[nf];
            }
}

extern "C" void kernel_launch(void* const* d_in, const int* in_sizes, int n_in,
                              void* d_out, int out_size, void* d_ws, size_t ws_size,
                              hipStream_t stream) {
    const float* x    = (const float*)d_in[0];
    const float* w    = (const float*)d_in[1];
    const float* bias = (const float*)d_in[2];
    const int*   row  = (const int*)d_in[3];
    const int*   col  = (const int*)d_in[4];
    float* out = (float*)d_out;
    const int nnz = in_sizes[3];

    // Workspace: xb (67 MB) + Wb (33.5 MB) in d_ws. Packed winner array P
    // (16.78M x 8B = 134 MB) borrows d_out (exactly 134 MB) -- GEMM
    // overwrites it after extract has consumed it.
    __bf16* xb = (__bf16*)d_ws;
    __bf16* Wb = (__bf16*)((char*)d_ws + (size_t)TOKENS * IN_F * 2);
    unsigned long long* P = (unsigned long long*)d_out;

    static bool attr_done = false;
    if (!attr_done) {
        hipFuncSetAttribute(reinterpret_cast<const void*>(gemm256_kernel),
                            hipFuncAttributeMaxDynamicSharedMemorySize, 131072);
        attr_done = true;
    }

    hipMemsetAsync(P, 0x00, (size_t)OUT_F * IN_F * 8, stream);  // P = 0

    const int sb = (nnz + 1023) / 1024;             // scatter blocks (4 nnz/thread)
    const int cb = TOKENS * IN_F / (256 * 8);       // 16384 convert blocks
    fused_scatter_convert_kernel<<<sb + cb, 256, 0, stream>>>(
        row, col, w, P, x, xb, sb, nnz);

    extract_kernel<<<OUT_F * IN_F / (256 * 8), 256, 0, stream>>>(P, Wb);

    dim3 grid(OUT_F / 256, TOKENS / 256);           // (16, 32) = 512 wgs
    gemm256_kernel<<<grid, 512, 131072, stream>>>(xb, Wb, bias, out);
}